// Round 1
// baseline (23.704 us; speedup 1.0000x reference)
//
#include <hip/hip_runtime.h>

// MovingAvgTime: out[b,j,c] = (1/k) * sum_{a=starts[j]}^{starts[j]+k-1} x[b,a,c]
// starts[j] = min( int( (j+0.5f) * float(ncols/L) ), ncols-1 ),  ncols = L-k+1
// Fixed shapes from setup_inputs: B=32, L=4096, C=64, fp32.

#define BB 32
#define LL 4096
#define CC 64
#define C4 16  // CC/4 float4 per row

__global__ __launch_bounds__(256) void mavg16_kernel(const float* __restrict__ x,
                                                     const int* __restrict__ kptr,
                                                     float* __restrict__ out) {
    const int k = *kptr;                      // 16 in practice
    const int ncols = LL - k + 1;
    // Python computes n_cols / L in double, then multiplies an fp32 array.
    const float cmap = (float)((double)ncols / (double)LL);

    // XCD-aware chunked swizzle: grid = 8192, divisible by 8 -> bijective.
    const int nwg = (int)gridDim.x;
    const int cpx = nwg >> 3;                 // chunks per XCD
    const int bid = (int)blockIdx.x;
    const int w = (bid & 7) * cpx + (bid >> 3);

    const int b    = w >> 8;                  // / 256 j-blocks per batch
    const int jblk = w & 255;

    const int c4 = threadIdx.x & 15;          // channel quad
    const int jl = threadIdx.x >> 4;          // 0..15 local j
    const int j  = jblk * 16 + jl;

    // Exact replication of the reference start index (f32 add, f32 mul, trunc)
    float fj = (float)j + 0.5f;
    int start = (int)(fj * cmap);
    start = min(start, ncols - 1);

    const float4* xb = (const float4*)x + (size_t)b * (LL * C4);
    float4 acc = make_float4(0.f, 0.f, 0.f, 0.f);

    if (k == 16) {
        #pragma unroll
        for (int a = 0; a < 16; ++a) {
            float4 v = xb[(size_t)(start + a) * C4 + c4];
            acc.x += v.x; acc.y += v.y; acc.z += v.z; acc.w += v.w;
        }
    } else {
        for (int a = 0; a < k; ++a) {
            float4 v = xb[(size_t)(start + a) * C4 + c4];
            acc.x += v.x; acc.y += v.y; acc.z += v.z; acc.w += v.w;
        }
    }

    const float inv = 1.0f / (float)k;
    acc.x *= inv; acc.y *= inv; acc.z *= inv; acc.w *= inv;

    float4* ob = (float4*)out + (size_t)b * (LL * C4);
    ob[(size_t)j * C4 + c4] = acc;
}

extern "C" void kernel_launch(void* const* d_in, const int* in_sizes, int n_in,
                              void* d_out, int out_size, void* d_ws, size_t ws_size,
                              hipStream_t stream) {
    const float* x    = (const float*)d_in[0];
    const int*   kptr = (const int*)d_in[1];
    float*       out  = (float*)d_out;
    // 32 batches * 256 j-blocks = 8192 blocks, 256 threads each.
    mavg16_kernel<<<dim3(8192), dim3(256), 0, stream>>>(x, kptr, out);
}

// Round 2
// 16.622 us; speedup vs baseline: 1.4261x; 1.4261x over previous
//
#include <hip/hip_runtime.h>

// MovingAvgTime: out[b,j,c] = (1/k) * sum_{a=starts[j]}^{starts[j]+k-1} x[b,a,c]
// starts[j] = min( int( (j+0.5f) * float(ncols/L) ), ncols-1 ),  ncols = L-k+1
// Shapes: B=32, L=4096, C=64, fp32. k=16 fast path uses a register sliding window:
// 16 loads for the first window, then 2 loads per subsequent j (ds in {0,1}).

#define BB 32
#define LL 4096
#define CC 64
#define C4 16   // CC/4 float4 per row
#define JPT 8   // consecutive j per thread
// block: 256 threads = 16 j-groups x 16 c4  -> covers 16*8 = 128 j
// jblocks per batch = 4096/128 = 32 ; grid = 32*32 = 1024 blocks

__global__ __launch_bounds__(256) void mavg16_kernel(const float* __restrict__ x,
                                                     const int* __restrict__ kptr,
                                                     float* __restrict__ out) {
    const int k = *kptr;
    const int ncols = LL - k + 1;
    const float cmap = (float)((double)ncols / (double)LL);

    // XCD-aware chunked swizzle (grid=1024, divisible by 8 -> bijective)
    const int nwg = (int)gridDim.x;
    const int cpx = nwg >> 3;
    const int bid = (int)blockIdx.x;
    const int w = (bid & 7) * cpx + (bid >> 3);

    const int b    = w >> 5;      // / 32 j-blocks per batch
    const int jblk = w & 31;

    const int c4  = threadIdx.x & 15;
    const int jgl = threadIdx.x >> 4;
    const int j0  = jblk * 128 + jgl * JPT;

    const float4* xb = (const float4*)x + (size_t)b * (LL * C4) + c4;
    float4*       ob = (float4*)out     + (size_t)b * (LL * C4) + c4;

    if (k == 16) {
        const float inv = 0.0625f;  // exact power of two
        int s0 = (int)(((float)j0 + 0.5f) * cmap);
        s0 = min(s0, ncols - 1);

        float4 acc = make_float4(0.f, 0.f, 0.f, 0.f);
        #pragma unroll
        for (int t = 0; t < 16; ++t) {
            float4 v = xb[(size_t)(s0 + t) * C4];
            acc.x += v.x; acc.y += v.y; acc.z += v.z; acc.w += v.w;
        }
        ob[(size_t)j0 * C4] = make_float4(acc.x * inv, acc.y * inv, acc.z * inv, acc.w * inv);

        int sp = s0;
        #pragma unroll
        for (int t = 1; t < JPT; ++t) {
            int sn = (int)(((float)(j0 + t) + 0.5f) * cmap);
            sn = min(sn, ncols - 1);
            // unconditional loads (hoistable); select makes the update branchless
            float4 ra = xb[(size_t)(sn + 15) * C4];  // row entering the window
            float4 rs = xb[(size_t)sp * C4];         // row leaving the window
            const bool slide = (sn != sp);
            acc.x += slide ? (ra.x - rs.x) : 0.0f;
            acc.y += slide ? (ra.y - rs.y) : 0.0f;
            acc.z += slide ? (ra.z - rs.z) : 0.0f;
            acc.w += slide ? (ra.w - rs.w) : 0.0f;
            sp = sn;
            ob[(size_t)(j0 + t) * C4] =
                make_float4(acc.x * inv, acc.y * inv, acc.z * inv, acc.w * inv);
        }
    } else {
        // generic fallback (correct for any k)
        const float inv = 1.0f / (float)k;
        for (int t = 0; t < JPT; ++t) {
            const int j = j0 + t;
            int s = (int)(((float)j + 0.5f) * cmap);
            s = min(s, ncols - 1);
            float4 acc = make_float4(0.f, 0.f, 0.f, 0.f);
            for (int a = 0; a < k; ++a) {
                float4 v = xb[(size_t)(s + a) * C4];
                acc.x += v.x; acc.y += v.y; acc.z += v.z; acc.w += v.w;
            }
            ob[(size_t)j * C4] =
                make_float4(acc.x * inv, acc.y * inv, acc.z * inv, acc.w * inv);
        }
    }
}

extern "C" void kernel_launch(void* const* d_in, const int* in_sizes, int n_in,
                              void* d_out, int out_size, void* d_ws, size_t ws_size,
                              hipStream_t stream) {
    const float* x    = (const float*)d_in[0];
    const int*   kptr = (const int*)d_in[1];
    float*       out  = (float*)d_out;
    mavg16_kernel<<<dim3(1024), dim3(256), 0, stream>>>(x, kptr, out);
}

// Round 3
// 16.220 us; speedup vs baseline: 1.4614x; 1.0248x over previous
//
#include <hip/hip_runtime.h>

// MovingAvgTime: out[b,j,c] = (1/k) * sum_{a=starts[j]}^{starts[j]+k-1} x[b,a,c]
// starts[j] = min( int( (j+0.5f) * float(ncols/L) ), ncols-1 ),  ncols = L-k+1
// Shapes: B=32, L=4096, C=64, fp32.
// k=16 path: stage the block's 144-row input window in LDS (one coalesced
// 36 KB copy -> near-ideal HBM fetch), then per-thread register sliding
// window reading from LDS.

#define LL   4096
#define C4   16    // float4 per row (C=64)
#define BJ   128   // j covered per block
#define NR   144   // rows staged: ceil(127*cmap)+16 = 143 -> pad to 144
#define JPT  8     // j per thread
// block: 256 threads = 16 j-groups x 16 c4 ; grid = 32 b * 32 jblk = 1024

__global__ __launch_bounds__(256) void mavg16_kernel(const float* __restrict__ x,
                                                     const int* __restrict__ kptr,
                                                     float* __restrict__ out) {
    __shared__ float4 lds[NR * C4];   // 36864 B -> 4 blocks/CU

    const int k = *kptr;
    const int ncols = LL - k + 1;
    const float cmap = (float)((double)ncols / (double)LL);

    // XCD-aware chunked swizzle (grid=1024, divisible by 8 -> bijective)
    const int nwg = (int)gridDim.x;
    const int cpx = nwg >> 3;
    const int bid = (int)blockIdx.x;
    const int w = (bid & 7) * cpx + (bid >> 3);

    const int b    = w >> 5;     // 32 jblocks per batch
    const int jblk = w & 31;
    const int j0b  = jblk * BJ;

    const int tid = (int)threadIdx.x;
    const int c4  = tid & 15;
    const int jgl = tid >> 4;

    const float4* xb = (const float4*)x + (size_t)b * (LL * C4);
    float4*       ob = (float4*)out     + (size_t)b * (LL * C4);

    if (k == 16) {
        int sbase = (int)(((float)j0b + 0.5f) * cmap);
        sbase = min(sbase, ncols - 1);

        // Stage rows [sbase, sbase+NR) into LDS: 2304 float4 = 9 per thread,
        // contiguous in both global and LDS (fully coalesced, conflict-free).
        const int base4 = sbase * C4;
        #pragma unroll
        for (int i = 0; i < 9; ++i) {
            int f = i * 256 + tid;
            int g = min(base4 + f, LL * C4 - 1);  // clamp (last jblk only; unused)
            lds[f] = xb[g];
        }
        __syncthreads();

        const float inv = 0.0625f;
        const int j0 = j0b + jgl * JPT;
        int s0 = (int)(((float)j0 + 0.5f) * cmap);
        s0 = min(s0, ncols - 1);
        const int r0 = s0 - sbase;

        float4 acc = make_float4(0.f, 0.f, 0.f, 0.f);
        #pragma unroll
        for (int t = 0; t < 16; ++t) {
            float4 v = lds[(r0 + t) * C4 + c4];
            acc.x += v.x; acc.y += v.y; acc.z += v.z; acc.w += v.w;
        }
        ob[(size_t)j0 * C4 + c4] =
            make_float4(acc.x * inv, acc.y * inv, acc.z * inv, acc.w * inv);

        int sp = r0;
        #pragma unroll
        for (int t = 1; t < JPT; ++t) {
            int sn = (int)(((float)(j0 + t) + 0.5f) * cmap);
            sn = min(sn, ncols - 1) - sbase;
            float4 ra = lds[(sn + 15) * C4 + c4];  // row entering
            float4 rs = lds[sp * C4 + c4];         // row leaving
            const bool slide = (sn != sp);
            acc.x += slide ? (ra.x - rs.x) : 0.0f;
            acc.y += slide ? (ra.y - rs.y) : 0.0f;
            acc.z += slide ? (ra.z - rs.z) : 0.0f;
            acc.w += slide ? (ra.w - rs.w) : 0.0f;
            sp = sn;
            ob[(size_t)(j0 + t) * C4 + c4] =
                make_float4(acc.x * inv, acc.y * inv, acc.z * inv, acc.w * inv);
        }
    } else {
        // generic fallback (any k), direct global reads
        const float inv = 1.0f / (float)k;
        for (int t = 0; t < JPT; ++t) {
            const int j = j0b + jgl * JPT + t;
            int s = (int)(((float)j + 0.5f) * cmap);
            s = min(s, ncols - 1);
            float4 acc = make_float4(0.f, 0.f, 0.f, 0.f);
            for (int a = 0; a < k; ++a) {
                float4 v = xb[(size_t)(s + a) * C4 + c4];
                acc.x += v.x; acc.y += v.y; acc.z += v.z; acc.w += v.w;
            }
            ob[(size_t)j * C4 + c4] =
                make_float4(acc.x * inv, acc.y * inv, acc.z * inv, acc.w * inv);
        }
    }
}

extern "C" void kernel_launch(void* const* d_in, const int* in_sizes, int n_in,
                              void* d_out, int out_size, void* d_ws, size_t ws_size,
                              hipStream_t stream) {
    const float* x    = (const float*)d_in[0];
    const int*   kptr = (const int*)d_in[1];
    float*       out  = (float*)d_out;
    mavg16_kernel<<<dim3(1024), dim3(256), 0, stream>>>(x, kptr, out);
}

// Round 4
// 14.365 us; speedup vs baseline: 1.6502x; 1.1292x over previous
//
#include <hip/hip_runtime.h>

// MovingAvgTime: out[b,j,c] = (1/k) * sum_{a=starts[j]}^{starts[j]+k-1} x[b,a,c]
// starts[j] = min( int( (j+0.5f) * float(ncols/L) ), ncols-1 ),  ncols = L-k+1
// Shapes: B=32, L=4096, C=64, fp32.
// k=16: stage 80-row window in LDS via global_load_lds (async, no VGPR trip),
// 20 KB LDS -> 8 blocks/CU (max occupancy), register sliding window from LDS,
// nontemporal stores.

#define LL   4096
#define C4   16    // float4 per row (C=64)
#define BJ   64    // j covered per block
#define NR   80    // rows staged (max needed 79)
#define JPT  4     // j per thread
#define NSTG 5     // staged float4 per thread = NR*C4/256
// block: 256 threads = 16 j-groups x 16 c4 ; grid = 32 b * 64 jblk = 2048

typedef float v4 __attribute__((ext_vector_type(4)));

__global__ __launch_bounds__(256) void mavg16_kernel(const float* __restrict__ x,
                                                     const int* __restrict__ kptr,
                                                     float* __restrict__ out) {
    __shared__ v4 lds[NR * C4];   // 20480 B -> 8 blocks/CU (160 KB exactly)

    const int k = *kptr;
    const int ncols = LL - k + 1;
    const float cmap = (float)((double)ncols / (double)LL);

    // XCD-aware chunked swizzle (grid=2048, divisible by 8 -> bijective)
    const int nwg = (int)gridDim.x;
    const int cpx = nwg >> 3;
    const int bid = (int)blockIdx.x;
    const int w = (bid & 7) * cpx + (bid >> 3);

    const int b    = w >> 6;      // 64 j-blocks per batch
    const int jblk = w & 63;
    const int j0b  = jblk * BJ;

    const int tid = (int)threadIdx.x;
    const int c4  = tid & 15;
    const int jgl = tid >> 4;

    const v4* xb = (const v4*)x + (size_t)b * (LL * C4);
    v4*       ob = (v4*)out     + (size_t)b * (LL * C4);

    if (k == 16) {
        int sbase = (int)(((float)j0b + 0.5f) * cmap);
        sbase = min(sbase, ncols - 1);
        const int base4 = sbase * C4;

        // Async stage: lane-linear LDS dest (wave-uniform base + lane*16),
        // per-lane global src (clamped only in the final block; rows unused).
        #pragma unroll
        for (int i = 0; i < NSTG; ++i) {
            const int f = i * 256 + tid;
            const int g = min(base4 + f, LL * C4 - 1);
            __builtin_amdgcn_global_load_lds(
                (const __attribute__((address_space(1))) unsigned int*)(xb + g),
                (__attribute__((address_space(3))) unsigned int*)&lds[f],
                16, 0, 0);
        }
        __syncthreads();   // drains vmcnt before any lane reads LDS

        const float inv = 0.0625f;
        const int j0 = j0b + jgl * JPT;
        int s0 = (int)(((float)j0 + 0.5f) * cmap);
        s0 = min(s0, ncols - 1);
        const int r0 = s0 - sbase;

        v4 acc = (v4){0.f, 0.f, 0.f, 0.f};
        #pragma unroll
        for (int t = 0; t < 16; ++t) {
            acc += lds[(r0 + t) * C4 + c4];
        }
        __builtin_nontemporal_store(acc * inv, &ob[(size_t)j0 * C4 + c4]);

        int sp = r0;
        #pragma unroll
        for (int t = 1; t < JPT; ++t) {
            int sn = (int)(((float)(j0 + t) + 0.5f) * cmap);
            sn = min(sn, ncols - 1) - sbase;
            v4 ra = lds[(sn + 15) * C4 + c4];  // row entering the window
            v4 rs = lds[sp * C4 + c4];         // row leaving the window
            if (sn != sp) acc += ra - rs;
            sp = sn;
            __builtin_nontemporal_store(acc * inv, &ob[(size_t)(j0 + t) * C4 + c4]);
        }
    } else {
        // generic fallback (any k), direct global reads
        const float inv = 1.0f / (float)k;
        for (int t = 0; t < JPT; ++t) {
            const int j = j0b + jgl * JPT + t;
            int s = (int)(((float)j + 0.5f) * cmap);
            s = min(s, ncols - 1);
            v4 acc = (v4){0.f, 0.f, 0.f, 0.f};
            for (int a = 0; a < k; ++a) {
                acc += xb[(size_t)(s + a) * C4 + c4];
            }
            ob[(size_t)j * C4 + c4] = acc * inv;
        }
    }
}

extern "C" void kernel_launch(void* const* d_in, const int* in_sizes, int n_in,
                              void* d_out, int out_size, void* d_ws, size_t ws_size,
                              hipStream_t stream) {
    const float* x    = (const float*)d_in[0];
    const int*   kptr = (const int*)d_in[1];
    float*       out  = (float*)d_out;
    mavg16_kernel<<<dim3(2048), dim3(256), 0, stream>>>(x, kptr, out);
}

// Round 5
// 13.806 us; speedup vs baseline: 1.7169x; 1.0404x over previous
//
#include <hip/hip_runtime.h>

// MovingAvgTime: out[b,j,c] = (1/k) * sum_{a=starts[j]}^{starts[j]+k-1} x[b,a,c]
// starts[j] = min( int( (j+0.5f) * float(ncols/L) ), ncols-1 ),  ncols = L-k+1
// Shapes: B=32, L=4096, C=64, fp32.
// k=16: two adjacent 64-j tiles per block, double-buffered LDS (40 KB,
// 4 blocks/CU). STAGE(A) + STAGE(B) issued up front via global_load_lds;
// counted s_waitcnt vmcnt(5) + raw s_barrier lets T0 compute/stores overlap
// T1's HBM reads (no vmcnt(0) drain mid-kernel). Nontemporal stores.

#define LL   4096
#define C4   16    // float4 per row (C=64)
#define BJ   64    // j per tile
#define NR   80    // rows staged per tile (max used 79)
#define JPT  4     // j per thread
#define NSTG 5     // gload_lds per thread per tile (NR*C4/256)
// block: 256 threads = 16 j-groups x 16 c4 ; grid = 32 b * 32 pairs = 1024

typedef float v4 __attribute__((ext_vector_type(4)));

__global__ __launch_bounds__(256) void mavg16_kernel(const float* __restrict__ x,
                                                     const int* __restrict__ kptr,
                                                     float* __restrict__ out) {
    __shared__ v4 lds[2 * NR * C4];   // 40960 B -> 4 blocks/CU

    const int k = *kptr;
    const int ncols = LL - k + 1;
    const float cmap = (float)((double)ncols / (double)LL);

    // XCD-aware chunked swizzle (grid=1024, divisible by 8 -> bijective)
    const int nwg = (int)gridDim.x;
    const int cpx = nwg >> 3;
    const int bid = (int)blockIdx.x;
    const int w = (bid & 7) * cpx + (bid >> 3);

    const int b  = w >> 5;      // 32 tile-pairs per batch
    const int pr = w & 31;
    const int j0_T0 = pr * 128;        // tile 0: j in [j0, j0+64)
    const int j0_T1 = pr * 128 + 64;   // tile 1: adjacent (halo = L2 hit)

    const int tid = (int)threadIdx.x;
    const int c4  = tid & 15;
    const int jgl = tid >> 4;

    const v4* xb = (const v4*)x + (size_t)b * (LL * C4);
    v4*       ob = (v4*)out     + (size_t)b * (LL * C4);

    if (k == 16) {
        int sb0 = min((int)(((float)j0_T0 + 0.5f) * cmap), ncols - 1);
        int sb1 = min((int)(((float)j0_T1 + 0.5f) * cmap), ncols - 1);

        // STAGE A (tile 0) then STAGE B (tile 1): 5+5 gload_lds per thread.
        #pragma unroll
        for (int i = 0; i < NSTG; ++i) {
            const int f = i * 256 + tid;
            const int g = min(sb0 * C4 + f, LL * C4 - 1);
            __builtin_amdgcn_global_load_lds(
                (const __attribute__((address_space(1))) unsigned int*)(xb + g),
                (__attribute__((address_space(3))) unsigned int*)&lds[f],
                16, 0, 0);
        }
        #pragma unroll
        for (int i = 0; i < NSTG; ++i) {
            const int f = i * 256 + tid;
            const int g = min(sb1 * C4 + f, LL * C4 - 1);
            __builtin_amdgcn_global_load_lds(
                (const __attribute__((address_space(1))) unsigned int*)(xb + g),
                (__attribute__((address_space(3))) unsigned int*)&lds[NR * C4 + f],
                16, 0, 0);
        }

        // Own A-loads done (B's 5 may remain in flight); then all waves' A done.
        asm volatile("s_waitcnt vmcnt(5)" ::: "memory");
        __builtin_amdgcn_s_barrier();

        const float inv = 0.0625f;

        // ---- compute tile 0 from buffer A (B reads still in flight) ----
        {
            const v4* buf = lds;
            const int j0 = j0_T0 + jgl * JPT;
            int s0 = min((int)(((float)j0 + 0.5f) * cmap), ncols - 1);
            const int r0 = s0 - sb0;
            v4 acc = (v4){0.f, 0.f, 0.f, 0.f};
            #pragma unroll
            for (int t = 0; t < 16; ++t) acc += buf[(r0 + t) * C4 + c4];
            __builtin_nontemporal_store(acc * inv, &ob[(size_t)j0 * C4 + c4]);
            int sp = r0;
            #pragma unroll
            for (int t = 1; t < JPT; ++t) {
                int sn = min((int)(((float)(j0 + t) + 0.5f) * cmap), ncols - 1) - sb0;
                v4 ra = buf[(sn + 15) * C4 + c4];
                v4 rs = buf[sp * C4 + c4];
                if (sn != sp) acc += ra - rs;
                sp = sn;
                __builtin_nontemporal_store(acc * inv, &ob[(size_t)(j0 + t) * C4 + c4]);
            }
        }

        // B's 5 loads retired (own 4 stores may remain outstanding).
        asm volatile("s_waitcnt vmcnt(4)" ::: "memory");
        __builtin_amdgcn_s_barrier();

        // ---- compute tile 1 from buffer B ----
        {
            const v4* buf = lds + NR * C4;
            const int j0 = j0_T1 + jgl * JPT;
            int s0 = min((int)(((float)j0 + 0.5f) * cmap), ncols - 1);
            const int r0 = s0 - sb1;
            v4 acc = (v4){0.f, 0.f, 0.f, 0.f};
            #pragma unroll
            for (int t = 0; t < 16; ++t) acc += buf[(r0 + t) * C4 + c4];
            __builtin_nontemporal_store(acc * inv, &ob[(size_t)j0 * C4 + c4]);
            int sp = r0;
            #pragma unroll
            for (int t = 1; t < JPT; ++t) {
                int sn = min((int)(((float)(j0 + t) + 0.5f) * cmap), ncols - 1) - sb1;
                v4 ra = buf[(sn + 15) * C4 + c4];
                v4 rs = buf[sp * C4 + c4];
                if (sn != sp) acc += ra - rs;
                sp = sn;
                __builtin_nontemporal_store(acc * inv, &ob[(size_t)(j0 + t) * C4 + c4]);
            }
        }
    } else {
        // generic fallback (any k), direct global reads, both tiles
        const float inv = 1.0f / (float)k;
        for (int tile = 0; tile < 2; ++tile) {
            const int j0b = (tile == 0) ? j0_T0 : j0_T1;
            for (int t = 0; t < JPT; ++t) {
                const int j = j0b + jgl * JPT + t;
                int s = min((int)(((float)j + 0.5f) * cmap), ncols - 1);
                v4 acc = (v4){0.f, 0.f, 0.f, 0.f};
                for (int a = 0; a < k; ++a) acc += xb[(size_t)(s + a) * C4 + c4];
                ob[(size_t)j * C4 + c4] = acc * inv;
            }
        }
    }
}

extern "C" void kernel_launch(void* const* d_in, const int* in_sizes, int n_in,
                              void* d_out, int out_size, void* d_ws, size_t ws_size,
                              hipStream_t stream) {
    const float* x    = (const float*)d_in[0];
    const int*   kptr = (const int*)d_in[1];
    float*       out  = (float*)d_out;
    mavg16_kernel<<<dim3(1024), dim3(256), 0, stream>>>(x, kptr, out);
}